// Round 3
// baseline (1289.047 us; speedup 1.0000x reference)
//
#include <hip/hip_runtime.h>

#define HH 64
#define WW 64
#define CC 128
#define HWSZ 4096   // 64*64

// ---------------------------------------------------------------------------
// Direct 3x3 conv v2, pad 1, stride 1.
// Block: 256 threads, 32x32 pixel tile, 4 output channels.
// Thread: 4 consecutive pixels (x) x 4 oc = 16 accumulators.
// Per ic-chunk: x staged in LDS (34x36 rows incl. halo, b128-aligned),
// weights staged in LDS [ic][k][4oc] -> one b128 broadcast per (ic,k).
// Inner (ic): 6 x b128 window reads + 9 w b128 reads + 144 FMA -> VALU-bound.
// BN_IN: y=relu(scale*x+shift) on input during staging. STATS: per-channel
// sum/sumsq via shfl reduce + atomics. ATOMIC: ic-split accumulation
// (offset conv), bias added on split 0 only, oc guarded vs oc_total.
// ---------------------------------------------------------------------------
template<int ICC, bool BN_IN, bool STATS, bool ATOMIC>
__global__ __launch_bounds__(256)
void conv3x3_k(const float* __restrict__ in, const float* __restrict__ wgt,
               const float* __restrict__ bias,
               const float* __restrict__ bnscale, const float* __restrict__ bnshift,
               float* __restrict__ out, float* __restrict__ ssum, float* __restrict__ ssq,
               int oc_total, int ocg_count, int n_split)
{
    __shared__ float xt[ICC][34 * 36];   // row stride 36 (144B, 16B-aligned)
    __shared__ float wt[ICC][9][4];
    const int tid = threadIdx.x;
    const int txq = (tid & 7) * 4;       // thread's 4-px quad within tile
    const int ty  = tid >> 3;            // 0..31
    const int bx = blockIdx.x * 32, by = blockIdx.y * 32;
    int z = blockIdx.z;
    const int split = z % n_split; z /= n_split;
    const int ocg = z % ocg_count;
    const int b = z / ocg_count;
    const int oc0 = ocg * 4;
    const int icps = CC / n_split;
    const int ic_start = split * icps;

    float acc[4][4];   // [px][oc]
#pragma unroll
    for (int o = 0; o < 4; ++o) {
        float bv = 0.f;
        if (!ATOMIC || split == 0)
            bv = (oc0 + o < oc_total) ? bias[oc0 + o] : 0.f;
#pragma unroll
        for (int p = 0; p < 4; ++p) acc[p][o] = bv;
    }

    const float* inb = in + (size_t)b * CC * HWSZ;

    for (int ic0 = ic_start; ic0 < ic_start + icps; ic0 += ICC) {
        __syncthreads();
        // stage x tile (+halo): rows 0..33 = gy by-1..by+32, cols 0..34 = gx bx-1..bx+33
        for (int i = tid; i < ICC * 34 * 36; i += 256) {
            int ic = i / (34 * 36);
            int rem = i - ic * (34 * 36);
            int r = rem / 36, cl = rem - r * 36;
            int gy = by + r - 1, gx = bx + cl - 1;
            float v = 0.f;
            if (cl < 35 && (unsigned)gy < (unsigned)HH && (unsigned)gx < (unsigned)WW) {
                v = inb[(ic0 + ic) * HWSZ + gy * WW + gx];
                if (BN_IN)
                    v = fmaxf(fmaf(v, bnscale[ic0 + ic], bnshift[ic0 + ic]), 0.f);
            }
            xt[ic][rem] = v;
        }
        // stage weights [ic][k][4oc]
        for (int i = tid; i < ICC * 36; i += 256) {
            int ic = i / 36;
            int rem = i - ic * 36;
            int k = rem >> 2, o = rem & 3;
            int oc = oc0 + o;
            wt[ic][k][o] = (oc < oc_total)
                ? wgt[((size_t)oc * CC + (ic0 + ic)) * 9 + k] : 0.f;
        }
        __syncthreads();
#pragma unroll
        for (int ic = 0; ic < ICC; ++ic) {
            float win[3][8];
#pragma unroll
            for (int ky = 0; ky < 3; ++ky) {
                const float4* rp = reinterpret_cast<const float4*>(&xt[ic][(ty + ky) * 36 + txq]);
                float4 lo = rp[0], hi = rp[1];
                win[ky][0] = lo.x; win[ky][1] = lo.y; win[ky][2] = lo.z; win[ky][3] = lo.w;
                win[ky][4] = hi.x; win[ky][5] = hi.y; win[ky][6] = hi.z; win[ky][7] = hi.w;
            }
#pragma unroll
            for (int k = 0; k < 9; ++k) {
                const int ky = k / 3, kx = k % 3;
                float4 w4 = *reinterpret_cast<const float4*>(&wt[ic][k][0]);
                float wv[4] = {w4.x, w4.y, w4.z, w4.w};
#pragma unroll
                for (int o = 0; o < 4; ++o)
#pragma unroll
                    for (int p = 0; p < 4; ++p)
                        acc[p][o] = fmaf(win[ky][p + kx], wv[o], acc[p][o]);
            }
        }
    }

    const int py = by + ty;
    const int px0 = bx + txq;
#pragma unroll
    for (int o = 0; o < 4; ++o) {
        int oc = oc0 + o;
        if (ATOMIC) {
            if (oc < oc_total) {
                float* op = out + ((size_t)b * oc_total + oc) * HWSZ + py * WW + px0;
#pragma unroll
                for (int p = 0; p < 4; ++p) atomicAdd(op + p, acc[p][o]);
            }
        } else {
            float4 v = make_float4(acc[0][o], acc[1][o], acc[2][o], acc[3][o]);
            *reinterpret_cast<float4*>(out + ((size_t)b * oc_total + oc) * HWSZ + py * WW + px0) = v;
        }
    }

    if (STATS) {
#pragma unroll
        for (int o = 0; o < 4; ++o) {
            float s = acc[0][o] + acc[1][o] + acc[2][o] + acc[3][o];
            float q = acc[0][o] * acc[0][o] + acc[1][o] * acc[1][o]
                    + acc[2][o] * acc[2][o] + acc[3][o] * acc[3][o];
            for (int d = 32; d > 0; d >>= 1) {
                s += __shfl_down(s, d);
                q += __shfl_down(q, d);
            }
            if ((tid & 63) == 0) {
                atomicAdd(&ssum[oc0 + o], s);
                atomicAdd(&ssq[oc0 + o], q);
            }
        }
    }
}

// ---------------------------------------------------------------------------
// Deformable 3x3 conv v2 (deform_groups=1, pad 1, stride 1, zero-pad).
// Block: 256 threads, 32x16 px tile, 8 oc. Thread: 2 px x 8 oc.
// FAST PATH (block-uniform when all |off| < 3): x staged in LDS with HALO=4
// ring (zero-filled outside image), per-tap base index + 4 bilinear weights
// precomputed in registers; gathers are adjacent-pair LDS reads; weights
// staged in LDS -> 2 b128 broadcasts per (ic,k).
// SLOW PATH: global gather with validity weights, recomputed per iteration
// (cold; keeps register pressure low).
// ---------------------------------------------------------------------------
__global__ __launch_bounds__(256)
void dconv_k(const float* __restrict__ x, const float* __restrict__ off,
             const float* __restrict__ wd, const float* __restrict__ bd,
             float* __restrict__ dout)
{
    __shared__ float xt[8][24 * 40];   // rows 24 (16+8), stride 40 -> 30.7KB
    __shared__ float wt[8][9][8];
    __shared__ int s_bad;
    const int tid = threadIdx.x;
    const int tx2 = (tid & 15) * 2;
    const int ty  = tid >> 4;          // 0..15
    const int bx = blockIdx.x * 32, by = blockIdx.y * 16;
    const int b   = blockIdx.z >> 4;
    const int oc0 = (blockIdx.z & 15) * 8;
    const int py = by + ty;

    // precompute per-px, per-tap LDS base + bilinear weights; flag big offsets
    int   bs[2][9];
    float w00[2][9], w01[2][9], w10[2][9], w11[2][9];
    bool bad = false;
#pragma unroll
    for (int p = 0; p < 2; ++p) {
        const int px = bx + tx2 + p;
        const float* ob = off + (size_t)b * 18 * HWSZ + py * WW + px;
#pragma unroll
        for (int k = 0; k < 9; ++k) {
            float dyv = ob[(2 * k + 0) * HWSZ];
            float dxv = ob[(2 * k + 1) * HWSZ];
            bad |= !(fabsf(dyv) < 3.f) | !(fabsf(dxv) < 3.f);
            float fy = (float)(py + k / 3 - 1) + dyv;
            float fx = (float)(px + k % 3 - 1) + dxv;
            float yl = floorf(fy), xl = floorf(fx);
            float ly = fy - yl, lx = fx - xl;
            bs[p][k] = ((int)yl - by + 4) * 40 + ((int)xl - bx + 4);
            w00[p][k] = (1.f - ly) * (1.f - lx);
            w01[p][k] = (1.f - ly) * lx;
            w10[p][k] = ly * (1.f - lx);
            w11[p][k] = ly * lx;
        }
    }
    if (tid == 0) s_bad = 0;
    __syncthreads();
    if (bad) atomicOr(&s_bad, 1);
    __syncthreads();
    const bool fast = (s_bad == 0);

    float acc[2][8];
#pragma unroll
    for (int o = 0; o < 8; ++o) {
        float bv = bd[oc0 + o];
        acc[0][o] = bv; acc[1][o] = bv;
    }

    const float* xb = x + (size_t)b * CC * HWSZ;

    if (fast) {
        for (int ic0 = 0; ic0 < CC; ic0 += 8) {
            __syncthreads();
            for (int i = tid; i < 8 * 24 * 40; i += 256) {
                int ic = i / (24 * 40);
                int rem = i - ic * (24 * 40);
                int r = rem / 40, cl = rem - r * 40;
                int gy = by + r - 4, gx = bx + cl - 4;
                float v = 0.f;
                if ((unsigned)gy < (unsigned)HH && (unsigned)gx < (unsigned)WW)
                    v = xb[(ic0 + ic) * HWSZ + gy * WW + gx];
                xt[ic][rem] = v;
            }
            for (int i = tid; i < 8 * 72; i += 256) {
                int ic = i / 72;
                int rem = i - ic * 72;
                int k = rem >> 3, o = rem & 7;
                wt[ic][k][o] = wd[((size_t)(oc0 + o) * CC + (ic0 + ic)) * 9 + k];
            }
            __syncthreads();
#pragma unroll
            for (int ic = 0; ic < 8; ++ic) {
                const float* base = xt[ic];
#pragma unroll
                for (int k = 0; k < 9; ++k) {
                    float4 wa = *reinterpret_cast<const float4*>(&wt[ic][k][0]);
                    float4 wb = *reinterpret_cast<const float4*>(&wt[ic][k][4]);
                    float wv[8] = {wa.x, wa.y, wa.z, wa.w, wb.x, wb.y, wb.z, wb.w};
#pragma unroll
                    for (int p = 0; p < 2; ++p) {
                        const float* pp = base + bs[p][k];
                        float s =      w00[p][k] * pp[0];
                        s = fmaf(w01[p][k], pp[1],  s);
                        s = fmaf(w10[p][k], pp[40], s);
                        s = fmaf(w11[p][k], pp[41], s);
#pragma unroll
                        for (int o = 0; o < 8; ++o)
                            acc[p][o] = fmaf(s, wv[o], acc[p][o]);
                    }
                }
            }
        }
    } else {
        // slow path: recompute sampling per iteration, global gathers
        for (int ic = 0; ic < CC; ++ic) {
            const float* xc = xb + ic * HWSZ;
#pragma unroll
            for (int p = 0; p < 2; ++p) {
                const int px = bx + tx2 + p;
                const float* ob = off + (size_t)b * 18 * HWSZ + py * WW + px;
#pragma unroll
                for (int k = 0; k < 9; ++k) {
                    float dyv = ob[(2 * k + 0) * HWSZ];
                    float dxv = ob[(2 * k + 1) * HWSZ];
                    float fy = (float)(py + k / 3 - 1) + dyv;
                    float fx = (float)(px + k % 3 - 1) + dxv;
                    float yl = floorf(fy), xl = floorf(fx);
                    float ly = fy - yl, lx = fx - xl;
                    int iy0 = (int)yl, ix0 = (int)xl;
                    int iy1 = iy0 + 1, ix1 = ix0 + 1;
                    float vy0 = (iy0 >= 0 && iy0 < HH) ? 1.f : 0.f;
                    float vy1 = (iy1 >= 0 && iy1 < HH) ? 1.f : 0.f;
                    float vx0 = (ix0 >= 0 && ix0 < WW) ? 1.f : 0.f;
                    float vx1 = (ix1 >= 0 && ix1 < WW) ? 1.f : 0.f;
                    int iy0c = min(max(iy0, 0), HH - 1), iy1c = min(max(iy1, 0), HH - 1);
                    int ix0c = min(max(ix0, 0), WW - 1), ix1c = min(max(ix1, 0), WW - 1);
                    float s =      (1.f - ly) * (1.f - lx) * vy0 * vx0 * xc[iy0c * WW + ix0c];
                    s = fmaf((1.f - ly) * lx * vy0 * vx1, xc[iy0c * WW + ix1c], s);
                    s = fmaf(ly * (1.f - lx) * vy1 * vx0, xc[iy1c * WW + ix0c], s);
                    s = fmaf(ly * lx         * vy1 * vx1, xc[iy1c * WW + ix1c], s);
                    const float* wp = wd + ((size_t)oc0 * CC + ic) * 9 + k;
#pragma unroll
                    for (int o = 0; o < 8; ++o)
                        acc[p][o] = fmaf(s, wp[o * CC * 9], acc[p][o]);
                }
            }
        }
    }

    float* ob = dout + ((size_t)b * CC + oc0) * HWSZ + py * WW + bx + tx2;
#pragma unroll
    for (int o = 0; o < 8; ++o) {
        float2 v = make_float2(acc[0][o], acc[1][o]);
        *reinterpret_cast<float2*>(ob + o * HWSZ) = v;
    }
}

// mean/var -> (scale, shift) per channel
__global__ void bnstat_k(const float* __restrict__ ssum, const float* __restrict__ ssq,
                         const float* __restrict__ g, const float* __restrict__ bet,
                         float* __restrict__ scale, float* __restrict__ shift)
{
    int c = threadIdx.x;
    const float invn = 1.f / (4.f * HWSZ);
    float mean = ssum[c] * invn;
    float var  = ssq[c] * invn - mean * mean;
    float sc = g[c] * rsqrtf(var + 1e-5f);
    scale[c] = sc;
    shift[c] = fmaf(-mean, sc, bet[c]);
}

// out = relu(dout + bn2(y2)), vectorized float4
__global__ __launch_bounds__(256)
void final_k(const float* __restrict__ dout, const float* __restrict__ y2,
             const float* __restrict__ scale, const float* __restrict__ shift,
             float* __restrict__ out)
{
    int i = blockIdx.x * 256 + threadIdx.x;       // over 2M/4 float4s
    int c = (i >> 10) & 127;                      // channel of this float4
    float4 d = reinterpret_cast<const float4*>(dout)[i];
    float4 y = reinterpret_cast<const float4*>(y2)[i];
    float sc = scale[c], sh = shift[c];
    float4 r;
    r.x = fmaxf(d.x + fmaf(y.x, sc, sh), 0.f);
    r.y = fmaxf(d.y + fmaf(y.y, sc, sh), 0.f);
    r.z = fmaxf(d.z + fmaf(y.z, sc, sh), 0.f);
    r.w = fmaxf(d.w + fmaf(y.w, sc, sh), 0.f);
    reinterpret_cast<float4*>(out)[i] = r;
}

extern "C" void kernel_launch(void* const* d_in, const int* in_sizes, int n_in,
                              void* d_out, int out_size, void* d_ws, size_t ws_size,
                              hipStream_t stream)
{
    const float* x     = (const float*)d_in[0];
    const float* w_off = (const float*)d_in[1];
    const float* b_off = (const float*)d_in[2];
    const float* w_d   = (const float*)d_in[3];
    const float* b_d   = (const float*)d_in[4];
    const float* w1    = (const float*)d_in[5];
    const float* b1    = (const float*)d_in[6];
    const float* g1    = (const float*)d_in[7];
    const float* be1   = (const float*)d_in[8];
    const float* w2    = (const float*)d_in[9];
    const float* b2    = (const float*)d_in[10];
    const float* g2    = (const float*)d_in[11];
    const float* be2   = (const float*)d_in[12];

    float* ws      = (float*)d_ws;
    float* off_buf = ws;                      // B*18*H*W       = 294912
    float* y1      = off_buf + 294912;        // B*C*H*W        = 2097152
    float* y2      = y1 + 2097152;
    float* dob     = y2 + 2097152;
    float* st      = dob + 2097152;           // 1024 floats of stats/params
    // st layout: sum1[128] sq1[128] sum2[128] sq2[128] scale1[128] shift1[128] scale2[128] shift2[128]

    hipMemsetAsync(off_buf, 0, 294912 * sizeof(float), stream);
    hipMemsetAsync(st, 0, 512 * sizeof(float), stream);

    // offset conv (18 ch, padded to 5 oc-groups of 4), ic-split 8, atomic
    conv3x3_k<8, false, false, true><<<dim3(2, 2, 4 * 5 * 8), 256, 0, stream>>>(
        x, w_off, b_off, nullptr, nullptr, off_buf, nullptr, nullptr, 18, 5, 8);

    // deformable conv -> dob
    dconv_k<<<dim3(2, 4, 4 * 16), 256, 0, stream>>>(x, off_buf, w_d, b_d, dob);

    // conv1 (+ BN1 stats) -> y1
    conv3x3_k<8, false, true, false><<<dim3(2, 2, 4 * 32), 256, 0, stream>>>(
        x, w1, b1, nullptr, nullptr, y1, st, st + 128, 128, 32, 1);
    bnstat_k<<<1, 128, 0, stream>>>(st, st + 128, g1, be1, st + 512, st + 640);

    // conv2 on relu(bn1(y1)) applied during tile load (+ BN2 stats) -> y2
    conv3x3_k<8, true, true, false><<<dim3(2, 2, 4 * 32), 256, 0, stream>>>(
        y1, w2, b2, st + 512, st + 640, y2, st + 256, st + 384, 128, 32, 1);
    bnstat_k<<<1, 128, 0, stream>>>(st + 256, st + 384, g2, be2, st + 768, st + 896);

    // out = relu(dob + bn2(y2))
    final_k<<<dim3(2048), 256, 0, stream>>>(dob, y2, st + 768, st + 896, (float*)d_out);
}